// Round 4
// baseline (113.325 us; speedup 1.0000x reference)
//
#include <hip/hip_runtime.h>
#include <math.h>

#define NBINS 15
#define TROWS 128
#define NC 100
#define BLOCK 512
#define TILE_BYTES (TROWS * NC * 4)     // 51200 B, contiguous copy of global
#define NCHUNK (TILE_BYTES / 1024)      // 50 x 1KB wave-chunks

typedef __attribute__((address_space(3))) unsigned int lds_u32;
typedef __attribute__((address_space(1))) const unsigned int glob_u32;

// gbins layout in d_ws: [0..14]=counts, [15..29]=sum_conf, [30..44]=sum_acc
__global__ __launch_bounds__(BLOCK, 2) void ece_main(const float* __restrict__ logits,
                                                     const int* __restrict__ labels,
                                                     const int* __restrict__ t_opt,
                                                     float* __restrict__ gbins,
                                                     int N) {
    __shared__ float s_tile[2][TROWS * NC];   // 2 x 51.2 KB double buffer
    __shared__ int   s_lab[2][TROWS];         // labels staged alongside
    __shared__ float s_cnt[NBINS], s_conf[NBINS], s_acc[NBINS];

    const int tid  = threadIdx.x;
    if (tid < NBINS) { s_cnt[tid] = 0.f; s_conf[tid] = 0.f; s_acc[tid] = 0.f; }

    const int lane = tid & 63;
    const int wv   = tid >> 6;       // wave 0..7
    const int r    = tid >> 2;       // row in tile 0..127
    const int q    = tid & 3;        // quarter of row

    const int tt = t_opt[0];
    float scale = (tt != 0) ? (1.0f / (float)tt) : 1.0f;
    asm volatile("" :: "v"(scale));  // materialize before staging (keep vmcnt stream clean)

    const int nTiles = (N + TROWS - 1) / TROWS;
    const int stride = gridDim.x;

    // logit chunks per wave: waves 0,1 -> 7 chunks; waves 2..7 -> 6 chunks (=50)
    const int cstart = wv * 6 + (wv < 2 ? wv : 2);
    const int cn     = 6 + (wv < 2 ? 1 : 0);
    // waves 2,3 additionally stage 64 labels each -> issued loads: wv<4 ? 7 : 6

    auto STAGE = [&](int buf, int tile) {
        const long long rbase = (long long)tile * TROWS;
        const int rowsHere  = min(TROWS, (int)(N - rbase));
        const int bytesHere = rowsHere * (NC * 4);
        const char* gsrc = (const char*)(logits + rbase * NC);
        #pragma unroll
        for (int i = 0; i < 7; ++i) {
            if (i < cn) {
                const int c   = cstart + i;
                int off = c * 1024 + lane * 16;
                off = off < bytesHere ? off : bytesHere - 16;  // clamp src, keep inst count exact
                __builtin_amdgcn_global_load_lds(
                    (glob_u32*)(gsrc + off),
                    (lds_u32*)((char*)&s_tile[buf][0] + c * 1024),  // wave-uniform base
                    16, 0, 0);
            }
        }
        if (wv == 2 || wv == 3) {
            int li = (wv - 2) * 64 + lane;
            li = li < rowsHere ? li : rowsHere - 1;             // clamp src
            __builtin_amdgcn_global_load_lds(
                (glob_u32*)(labels + rbase + li),
                (lds_u32*)&s_lab[buf][(wv - 2) * 64],
                4, 0, 0);
        }
    };

    int cur = 0;
    if (blockIdx.x < nTiles) STAGE(0, blockIdx.x);

    for (int t0 = blockIdx.x; t0 < nTiles; t0 += stride) {
        const int nxt = t0 + stride;
        const bool hasNext = nxt < nTiles;
        if (hasNext) STAGE(cur ^ 1, nxt);

        // wait for CURRENT tile's loads only; keep next tile's in flight
        if (hasNext) {
            if (wv < 4) asm volatile("s_waitcnt vmcnt(7)" ::: "memory");
            else        asm volatile("s_waitcnt vmcnt(6)" ::: "memory");
        } else {
            asm volatile("s_waitcnt vmcnt(0)" ::: "memory");
        }
        __builtin_amdgcn_sched_barrier(0);
        __builtin_amdgcn_s_barrier();
        __builtin_amdgcn_sched_barrier(0);

        // ---- compute tile t0 from buf cur: 4 threads/row ----
        const long long rbase = (long long)t0 * TROWS;
        if (rbase + r < N) {
            const float4* rowp = (const float4*)&s_tile[cur][r * NC];
            const int nf = (q == 0) ? 7 : 6;
            const int fb = (q == 0) ? 0 : (1 + q * 6);   // f4 ranges: 0-6,7-12,13-18,19-24

            float4 v[7];
            #pragma unroll
            for (int j = 0; j < 7; ++j)
                if (j < nf) v[j] = rowp[fb + j];          // ds_read_b128, static idx

            float m = -INFINITY; int mi = 0;
            #pragma unroll
            for (int j = 0; j < 7; ++j) if (j < nf) {
                const int cb = (fb + j) * 4;
                float4 w = v[j];
                w.x *= scale; w.y *= scale; w.z *= scale; w.w *= scale;
                v[j] = w;
                if (w.x > m) { m = w.x; mi = cb;     }
                if (w.y > m) { m = w.y; mi = cb + 1; }
                if (w.z > m) { m = w.z; mi = cb + 2; }
                if (w.w > m) { m = w.w; mi = cb + 3; }
            }
            #pragma unroll
            for (int off = 1; off <= 2; off <<= 1) {
                const float om  = __shfl_xor(m, off);
                const int   omi = __shfl_xor(mi, off);
                if (om > m || (om == m && omi < mi)) { m = om; mi = omi; }
            }

            float e = 0.f;
            #pragma unroll
            for (int j = 0; j < 7; ++j) if (j < nf) {
                const float4 w = v[j];
                e += __expf(w.x - m) + __expf(w.y - m)
                   + __expf(w.z - m) + __expf(w.w - m);
            }
            e += __shfl_xor(e, 1);
            e += __shfl_xor(e, 2);

            if (q == 0) {
                const float conf = 1.0f / e;
                const float acc  = (mi == s_lab[cur][r]) ? 1.0f : 0.0f;

                // searchsorted(linspace(0,1,16), conf, 'left') - 1, clipped
                int jc = 0;
                #pragma unroll
                for (int i = 0; i <= NBINS; ++i) {
                    const float b = (float)i * (1.0f / 15.0f);
                    jc += (b < conf) ? 1 : 0;
                }
                int bin = jc - 1;
                bin = bin < 0 ? 0 : (bin > NBINS - 1 ? NBINS - 1 : bin);

                atomicAdd(&s_cnt[bin],  1.0f);
                atomicAdd(&s_conf[bin], conf);
                atomicAdd(&s_acc[bin],  acc);
            }
        }

        __builtin_amdgcn_sched_barrier(0);
        __builtin_amdgcn_s_barrier();      // protect buf cur before next iter's STAGE
        __builtin_amdgcn_sched_barrier(0);
        cur ^= 1;
    }

    // drain this wave's DS ops (hist atomics), then block-wide barrier, then flush
    asm volatile("s_waitcnt lgkmcnt(0)" ::: "memory");
    __builtin_amdgcn_sched_barrier(0);
    __builtin_amdgcn_s_barrier();
    __builtin_amdgcn_sched_barrier(0);

    if (tid < NBINS) {
        atomicAdd(&gbins[tid],             s_cnt[tid]);
        atomicAdd(&gbins[NBINS + tid],     s_conf[tid]);
        atomicAdd(&gbins[2 * NBINS + tid], s_acc[tid]);
    }
}

__global__ void ece_final(const float* __restrict__ gbins,
                          float* __restrict__ out, int N) {
    if (threadIdx.x == 0 && blockIdx.x == 0) {
        float ece = 0.f;
        for (int b = 0; b < NBINS; ++b) {
            const float c = gbins[b];
            if (c > 0.f) {
                const float avg_conf = gbins[NBINS + b] / c;
                const float avg_acc  = gbins[2 * NBINS + b] / c;
                ece += fabsf(avg_conf - avg_acc) * (c / (float)N);
            }
        }
        out[0] = ece;
    }
}

extern "C" void kernel_launch(void* const* d_in, const int* in_sizes, int n_in,
                              void* d_out, int out_size, void* d_ws, size_t ws_size,
                              hipStream_t stream) {
    const float* logits = (const float*)d_in[0];
    const int*   labels = (const int*)d_in[1];
    const int*   t_opt  = (const int*)d_in[2];
    float* out   = (float*)d_out;
    float* gbins = (float*)d_ws;

    const int N = in_sizes[1];               // 1,000,000 rows (C fixed at 100)

    hipMemsetAsync(gbins, 0, 3 * NBINS * sizeof(float), stream);

    const int nTiles = (N + TROWS - 1) / TROWS;
    const int blocks = nTiles < 256 ? nTiles : 256;   // 1 block/CU (102.4 KB LDS)
    ece_main<<<blocks, BLOCK, 0, stream>>>(logits, labels, t_opt, gbins, N);
    ece_final<<<1, 64, 0, stream>>>(gbins, out, N);
}

// Round 5
// 100.521 us; speedup vs baseline: 1.1274x; 1.1274x over previous
//
#include <hip/hip_runtime.h>
#include <math.h>

#define NBINS 15
#define TROWS 64
#define NC 100
#define BLOCK 256
#define TILE_BYTES (TROWS * NC * 4)     // 25600 B, contiguous copy of global
#define NCHUNK (TILE_BYTES / 1024)      // 25 x 1KB wave-chunks

typedef __attribute__((address_space(3))) unsigned int lds_u32;
typedef __attribute__((address_space(1))) const unsigned int glob_u32;

// gbins layout in d_ws: [0..14]=counts, [15..29]=sum_conf, [30..44]=sum_acc
__global__ __launch_bounds__(BLOCK, 3) void ece_main(const float* __restrict__ logits,
                                                     const int* __restrict__ labels,
                                                     const int* __restrict__ t_opt,
                                                     float* __restrict__ gbins,
                                                     int N) {
    __shared__ float s_tile[2][TROWS * NC];   // 2 x 25.6 KB double buffer
    __shared__ int   s_lab[2][TROWS];
    __shared__ float s_cnt[NBINS], s_conf[NBINS], s_acc[NBINS];

    const int tid  = threadIdx.x;
    if (tid < NBINS) { s_cnt[tid] = 0.f; s_conf[tid] = 0.f; s_acc[tid] = 0.f; }

    const int lane = tid & 63;
    const int wv   = tid >> 6;       // wave 0..3
    const int r    = tid >> 2;       // row in tile 0..63
    const int q    = tid & 3;        // quarter of row

    const int tt = t_opt[0];
    float scale = (tt != 0) ? (1.0f / (float)tt) : 1.0f;
    asm volatile("" :: "v"(scale));  // materialize before staging (keep vmcnt stream clean)

    const int nTiles = (N + TROWS - 1) / TROWS;
    const int stride = gridDim.x;

    // chunk split: wave0: 0-5 (+labels), wave1: 6-11, wave2: 12-17, wave3: 18-24
    const int cstart = wv * 6;
    const int cn     = (wv == 3) ? 7 : 6;
    const int myVm   = (wv == 0 || wv == 3) ? 7 : 6;   // loads issued per STAGE

    auto STAGE = [&](int buf, int tile) {
        const long long rbase = (long long)tile * TROWS;
        const int rowsHere  = min(TROWS, (int)(N - rbase));
        const int bytesHere = rowsHere * (NC * 4);
        const char* gsrc = (const char*)(logits + rbase * NC);
        #pragma unroll
        for (int i = 0; i < 7; ++i) {
            if (i < cn) {
                const int c = cstart + i;
                int off = c * 1024 + lane * 16;
                off = off < bytesHere ? off : bytesHere - 16;  // clamp src, keep inst count exact
                __builtin_amdgcn_global_load_lds(
                    (glob_u32*)(gsrc + off),
                    (lds_u32*)((char*)&s_tile[buf][0] + c * 1024),  // wave-uniform base
                    16, 0, 0);
            }
        }
        if (wv == 0) {
            int li = lane < rowsHere ? lane : rowsHere - 1;     // clamp src
            __builtin_amdgcn_global_load_lds(
                (glob_u32*)(labels + rbase + li),
                (lds_u32*)&s_lab[buf][0],
                4, 0, 0);
        }
    };

    int cur = 0;
    if (blockIdx.x < nTiles) STAGE(0, blockIdx.x);
    asm volatile("s_waitcnt lgkmcnt(0)" ::: "memory");   // s_cnt init visible at barrier

    for (int t0 = blockIdx.x; t0 < nTiles; t0 += stride) {
        const int nxt = t0 + stride;
        const bool hasNext = nxt < nTiles;
        if (hasNext) STAGE(cur ^ 1, nxt);

        // wait for CURRENT tile's loads only; keep next tile's in flight
        if (hasNext) {
            if (wv == 0 || wv == 3) asm volatile("s_waitcnt vmcnt(7)" ::: "memory");
            else                    asm volatile("s_waitcnt vmcnt(6)" ::: "memory");
        } else {
            asm volatile("s_waitcnt vmcnt(0)" ::: "memory");
        }
        __builtin_amdgcn_sched_barrier(0);
        __builtin_amdgcn_s_barrier();
        __builtin_amdgcn_sched_barrier(0);

        // ---- compute tile t0 from buf cur: 4 threads/row ----
        const long long rbase = (long long)t0 * TROWS;
        if (rbase + r < N) {
            const float4* rowp = (const float4*)&s_tile[cur][r * NC];
            const int nf = (q == 0) ? 7 : 6;
            const int fb = (q == 0) ? 0 : (1 + q * 6);   // f4 ranges: 0-6,7-12,13-18,19-24

            float4 v[7];
            #pragma unroll
            for (int j = 0; j < 7; ++j)
                if (j < nf) v[j] = rowp[fb + j];          // ds_read_b128, static idx

            float m = -INFINITY; int mi = 0;
            #pragma unroll
            for (int j = 0; j < 7; ++j) if (j < nf) {
                const int cb = (fb + j) * 4;
                float4 w = v[j];
                w.x *= scale; w.y *= scale; w.z *= scale; w.w *= scale;
                v[j] = w;
                if (w.x > m) { m = w.x; mi = cb;     }
                if (w.y > m) { m = w.y; mi = cb + 1; }
                if (w.z > m) { m = w.z; mi = cb + 2; }
                if (w.w > m) { m = w.w; mi = cb + 3; }
            }
            #pragma unroll
            for (int off = 1; off <= 2; off <<= 1) {
                const float om  = __shfl_xor(m, off);
                const int   omi = __shfl_xor(mi, off);
                if (om > m || (om == m && omi < mi)) { m = om; mi = omi; }
            }

            float e = 0.f;
            #pragma unroll
            for (int j = 0; j < 7; ++j) if (j < nf) {
                const float4 w = v[j];
                e += __expf(w.x - m) + __expf(w.y - m)
                   + __expf(w.z - m) + __expf(w.w - m);
            }
            e += __shfl_xor(e, 1);
            e += __shfl_xor(e, 2);

            if (q == 0) {
                const float conf = 1.0f / e;
                const float acc  = (mi == s_lab[cur][r]) ? 1.0f : 0.0f;

                // searchsorted(linspace(0,1,16), conf, 'left') - 1, clipped
                int jc = 0;
                #pragma unroll
                for (int i = 0; i <= NBINS; ++i) {
                    const float b = (float)i * (1.0f / 15.0f);
                    jc += (b < conf) ? 1 : 0;
                }
                int bin = jc - 1;
                bin = bin < 0 ? 0 : (bin > NBINS - 1 ? NBINS - 1 : bin);

                atomicAdd(&s_cnt[bin],  1.0f);
                atomicAdd(&s_conf[bin], conf);
                atomicAdd(&s_acc[bin],  acc);
            }
        }

        __builtin_amdgcn_sched_barrier(0);
        __builtin_amdgcn_s_barrier();      // protect buf cur before next iter's STAGE
        __builtin_amdgcn_sched_barrier(0);
        cur ^= 1;
    }

    // drain this wave's DS ops (hist atomics), then block-wide barrier, then flush
    asm volatile("s_waitcnt lgkmcnt(0)" ::: "memory");
    __builtin_amdgcn_sched_barrier(0);
    __builtin_amdgcn_s_barrier();
    __builtin_amdgcn_sched_barrier(0);

    if (tid < NBINS) {
        atomicAdd(&gbins[tid],             s_cnt[tid]);
        atomicAdd(&gbins[NBINS + tid],     s_conf[tid]);
        atomicAdd(&gbins[2 * NBINS + tid], s_acc[tid]);
    }
}

__global__ void ece_final(const float* __restrict__ gbins,
                          float* __restrict__ out, int N) {
    if (threadIdx.x == 0 && blockIdx.x == 0) {
        float ece = 0.f;
        for (int b = 0; b < NBINS; ++b) {
            const float c = gbins[b];
            if (c > 0.f) {
                const float avg_conf = gbins[NBINS + b] / c;
                const float avg_acc  = gbins[2 * NBINS + b] / c;
                ece += fabsf(avg_conf - avg_acc) * (c / (float)N);
            }
        }
        out[0] = ece;
    }
}

extern "C" void kernel_launch(void* const* d_in, const int* in_sizes, int n_in,
                              void* d_out, int out_size, void* d_ws, size_t ws_size,
                              hipStream_t stream) {
    const float* logits = (const float*)d_in[0];
    const int*   labels = (const int*)d_in[1];
    const int*   t_opt  = (const int*)d_in[2];
    float* out   = (float*)d_out;
    float* gbins = (float*)d_ws;

    const int N = in_sizes[1];               // 1,000,000 rows (C fixed at 100)

    hipMemsetAsync(gbins, 0, 3 * NBINS * sizeof(float), stream);

    const int nTiles = (N + TROWS - 1) / TROWS;
    const int blocks = nTiles < 768 ? nTiles : 768;   // 3 blocks/CU x 256 CU
    ece_main<<<blocks, BLOCK, 0, stream>>>(logits, labels, t_opt, gbins, N);
    ece_final<<<1, 64, 0, stream>>>(gbins, out, N);
}